// Round 6
// baseline (1657.403 us; speedup 1.0000x reference)
//
#include <hip/hip_runtime.h>
#include <hip/hip_fp16.h>

typedef _Float16 half8 __attribute__((ext_vector_type(8)));
typedef float floatx4 __attribute__((ext_vector_type(4)));

// workspace layout
// h exchange: [parity][group][dim][2] ulong, each = {tag16, hb_lo16, hb_hi16, 0}
#define HBUF_BYTES (2ull * 16 * 1024 * 2 * 8)   // 512 KB
#define CTL_BYTES  (32ull * 1024)               // flag words, 64 B each
#define XP_OFF     (HBUF_BYTES + CTL_BYTES)
#define XP_BYTES   (512ull * 64 * 1024 * 2)     // x_proj f16 [t][b][dim] = 64 MB
#define FLAG_STRIDE 16                          // ints -> 64 B per member flag

union hbits { _Float16 f; unsigned short s; };

__device__ inline half8 cvt8(const float4 a, const float4 b) {
    half8 r;
    r[0] = (_Float16)a.x; r[1] = (_Float16)a.y; r[2] = (_Float16)a.z; r[3] = (_Float16)a.w;
    r[4] = (_Float16)b.x; r[5] = (_Float16)b.y; r[6] = (_Float16)b.z; r[7] = (_Float16)b.w;
    return r;
}

// ---------------------------------------------------------------------------
// Phase A: x_proj[t][b][n] = sum_k emb[src[b][t]][k] * W_xh[n][k] + b_xh[n]
// (unchanged — ~290 us, next target once phase B is < ~0.5 ms)
// ---------------------------------------------------------------------------
__global__ __launch_bounds__(256) void xproj_kernel(
    const int* __restrict__ src, const float* __restrict__ emb,
    const float* __restrict__ Wxh, const float* __restrict__ bxh,
    _Float16* __restrict__ xp)
{
    __shared__ _Float16 As[128][40];
    __shared__ _Float16 Bs[128][40];

    const int tid  = threadIdx.x;
    const int lane = tid & 63;
    const int w    = tid >> 6;
    const int m15  = lane & 15;
    const int quad = lane >> 4;
    const int bid  = blockIdx.x;
    const int bn   = bid & 7;
    const int bm   = bid >> 3;
    const int m0   = bm * 128, n0 = bn * 128;
    const int wm   = w & 1, wn = w >> 1;

    const int  srow = tid >> 1;
    const int  scol = (tid & 1) * 16;
    const long arow = (long)src[m0 + srow] * 1024;
    const float* abase = emb + arow + scol;
    const float* bbase = Wxh + (long)(n0 + srow) * 1024 + scol;

    floatx4 zero4 = {0.f, 0.f, 0.f, 0.f};
    floatx4 acc[4][4];
#pragma unroll
    for (int mt = 0; mt < 4; mt++)
#pragma unroll
        for (int nt = 0; nt < 4; nt++) acc[mt][nt] = zero4;

    for (int k0 = 0; k0 < 1024; k0 += 32) {
        __syncthreads();
        float4 a0 = *(const float4*)(abase + k0);
        float4 a1 = *(const float4*)(abase + k0 + 4);
        float4 a2 = *(const float4*)(abase + k0 + 8);
        float4 a3 = *(const float4*)(abase + k0 + 12);
        float4 b0 = *(const float4*)(bbase + k0);
        float4 b1 = *(const float4*)(bbase + k0 + 4);
        float4 b2 = *(const float4*)(bbase + k0 + 8);
        float4 b3 = *(const float4*)(bbase + k0 + 12);
        *(half8*)&As[srow][scol]     = cvt8(a0, a1);
        *(half8*)&As[srow][scol + 8] = cvt8(a2, a3);
        *(half8*)&Bs[srow][scol]     = cvt8(b0, b1);
        *(half8*)&Bs[srow][scol + 8] = cvt8(b2, b3);
        __syncthreads();

        half8 af[4], bf[4];
#pragma unroll
        for (int mt = 0; mt < 4; mt++)
            af[mt] = *(const half8*)&As[wm * 64 + mt * 16 + m15][quad * 8];
#pragma unroll
        for (int nt = 0; nt < 4; nt++)
            bf[nt] = *(const half8*)&Bs[wn * 64 + nt * 16 + m15][quad * 8];
#pragma unroll
        for (int mt = 0; mt < 4; mt++)
#pragma unroll
            for (int nt = 0; nt < 4; nt++)
                acc[mt][nt] = __builtin_amdgcn_mfma_f32_16x16x32_f16(
                    af[mt], bf[nt], acc[mt][nt], 0, 0, 0);
    }

#pragma unroll
    for (int nt = 0; nt < 4; nt++) {
        const int n = n0 + wn * 64 + nt * 16 + m15;
        const float bias = bxh[n];
#pragma unroll
        for (int mt = 0; mt < 4; mt++) {
            const int mrow = m0 + wm * 64 + mt * 16 + quad * 4;
#pragma unroll
            for (int r = 0; r < 4; r++) {
                const int m = mrow + r;
                const int b = m >> 9;
                const int t = m & 511;
                xp[((long)t * 64 + b) * 1024 + n] = (_Float16)(acc[mt][nt][r] + bias);
            }
        }
    }
}

// ---------------------------------------------------------------------------
// Phase B: persistent recurrence, plain launch (256 WGs, 1 WG/CU guaranteed).
// R6 SYNC = R4 flag-gating + R5 tag-in-data, combined:
//   producer: tagged h stores -> __syncthreads (vmcnt(0) drain) -> flag store
//   consumer: issue ONE speculative pass of tagged h loads (stay in flight),
//             16-lane parallel flag poll (quiesced lines — cheap),
//             then validate tags; reload only stale words (bounded: flags>=t
//             proves all stores drained). Saves the post-flag gather trip.
// R5 lesson (measured): continuous polling of contended data lines blows up
// MALL write traffic (70->262 MB) — never spin on data lines pre-flag.
// Parity double-buffer: flag=t implies reader finished tag t-1 => overwrite
// of parity (t+1)&1 (holding tag t-1) is safe. 2-deep pipeline invariant.
// ---------------------------------------------------------------------------
__global__ __launch_bounds__(256, 1) void rnn_kernel(
    const float* __restrict__ Whh, const _Float16* __restrict__ xp,
    unsigned long long* __restrict__ hb, int* __restrict__ flags,
    float* __restrict__ out)
{
    __shared__ _Float16 hstage[16][1032];       // rows 4..15 stay zero (M-pad)
    __shared__ floatx4  cred[4][4][64];         // [k-slice wave][ntile][lane]

    const int tid    = threadIdx.x;
    const int lane   = tid & 63;
    const int w      = tid >> 6;
    const int m15    = lane & 15;
    const int quad   = lane >> 4;
    const int wg     = blockIdx.x;
    const int g      = wg & 15;
    const int member = wg >> 4;
    const int b0     = g * 4;

    for (int i = tid; i < 16 * 1032; i += 256) ((_Float16*)hstage)[i] = (_Float16)0.f;

    // W_hh slice -> 128 VGPRs (f16), reused for all 512 steps
    half8 Wf[4][8];
#pragma unroll
    for (int nt = 0; nt < 4; nt++) {
        const float* wrow = Whh + (long)(member * 64 + nt * 16 + m15) * 1024
                                + w * 256 + quad * 8;
#pragma unroll
        for (int kk = 0; kk < 8; kk++) {
            float4 lo = *(const float4*)(wrow + kk * 32);
            float4 hi = *(const float4*)(wrow + kk * 32 + 4);
            Wf[nt][kk] = cvt8(lo, hi);
        }
    }
    __syncthreads();

    const int dim = member * 64 + w * 16 + m15;
    float xv[4] = {0.f, 0.f, 0.f, 0.f};
    if (quad == 0) {
#pragma unroll
        for (int r = 0; r < 4; r++)
            xv[r] = (float)xp[((long)0 * 64 + b0 + r) * 1024 + dim];
    }

    int* myflag = flags + (g * 16 + member) * FLAG_STRIDE;
    const int* gflags = flags + g * 16 * FLAG_STRIDE;
    floatx4 zero4 = {0.f, 0.f, 0.f, 0.f};

    for (int t = 0; t < 512; t++) {
        // ---- speculative tagged h loads: ONE pass, in flight during poll --
        const unsigned long long* hg =
            hb + (size_t)(t & 1) * 32768 + (size_t)g * 2048 + (size_t)tid * 8;
        unsigned long long v[8];
#pragma unroll
        for (int j = 0; j < 8; j++)
            v[j] = __hip_atomic_load(hg + j, __ATOMIC_RELAXED,
                                     __HIP_MEMORY_SCOPE_AGENT);

        // ---- flag gate: lanes 0..15 of wave 0 poll quiesced flag lines ----
        if (t > 0) {
            if (tid < 16) {
                const int* fw = gflags + tid * FLAG_STRIDE;
                while (__hip_atomic_load(fw, __ATOMIC_RELAXED,
                                         __HIP_MEMORY_SCOPE_AGENT) < t) { }
            }
            __syncthreads();
        }

        // ---- validate tags; reload only stale words (bounded post-flag) ---
        {
            const unsigned tagu = (unsigned)t;
            for (;;) {
                unsigned bad = 0;
#pragma unroll
                for (int j = 0; j < 8; j++)
                    if ((unsigned)(v[j] & 0xffffu) != tagu) bad |= (1u << j);
                if (!bad) break;
#pragma unroll
                for (int j = 0; j < 8; j++)
                    if (bad & (1u << j))
                        v[j] = __hip_atomic_load(hg + j, __ATOMIC_RELAXED,
                                                 __HIP_MEMORY_SCOPE_AGENT);
            }
            // unpack: word e*2+(b>>1) holds dim (4*tid+e), batch pair (b&1)
#pragma unroll
            for (int b = 0; b < 4; b++) {
                unsigned long long q = 0;
#pragma unroll
                for (int e = 0; e < 4; e++) {
                    unsigned long long x =
                        (v[e * 2 + (b >> 1)] >> (16 + 16 * (b & 1))) & 0xffffu;
                    q |= x << (16 * e);
                }
                *(unsigned long long*)&hstage[b][tid * 4] = q;
            }
        }
        __syncthreads();

        // partial GEMM over this wave's K-slice, 4 n-tiles
        floatx4 pacc[4];
#pragma unroll
        for (int nt = 0; nt < 4; nt++) pacc[nt] = zero4;
#pragma unroll
        for (int kk = 0; kk < 8; kk++) {
            half8 a = *(const half8*)&hstage[m15][w * 256 + kk * 32 + quad * 8];
#pragma unroll
            for (int nt = 0; nt < 4; nt++)
                pacc[nt] = __builtin_amdgcn_mfma_f32_16x16x32_f16(
                    a, Wf[nt][kk], pacc[nt], 0, 0, 0);
        }

        // cross-wave K reduction via LDS; wave w finalizes n-tile w
#pragma unroll
        for (int nt = 0; nt < 4; nt++) cred[w][nt][lane] = pacc[nt];
        __syncthreads();
        floatx4 dsum = cred[0][w][lane];
#pragma unroll
        for (int ww = 1; ww < 4; ww++) dsum += cred[ww][w][lane];

        // epilogue: quad 0 holds batches 0..3; pack 2 tagged words, store.
        if (quad == 0) {
            hbits hv[4];
#pragma unroll
            for (int r = 0; r < 4; r++) {
                float pre  = dsum[r] + xv[r];
                float e    = __expf(2.0f * pre);
                float hval = 1.0f - 2.0f / (e + 1.0f);   // tanh
                hv[r].f = (_Float16)hval;
                if (t == 511) out[(b0 + r) * 1024 + dim] = hval;
            }
            const unsigned long long tag1 = (unsigned long long)(unsigned)(t + 1);
            unsigned long long w0 = tag1 | ((unsigned long long)hv[0].s << 16)
                                         | ((unsigned long long)hv[1].s << 32);
            unsigned long long w1 = tag1 | ((unsigned long long)hv[2].s << 16)
                                         | ((unsigned long long)hv[3].s << 32);
            unsigned long long* hw =
                hb + (size_t)((t + 1) & 1) * 32768 + (size_t)g * 2048
                   + (size_t)dim * 2;
            __hip_atomic_store(hw,     w0, __ATOMIC_RELAXED, __HIP_MEMORY_SCOPE_AGENT);
            __hip_atomic_store(hw + 1, w1, __ATOMIC_RELAXED, __HIP_MEMORY_SCOPE_AGENT);
        }

        // publish: barrier drains every wave's vmcnt(0) -> h stores acked,
        // then one relaxed flag store (tags make data self-validating anyway,
        // but the drain keeps the post-flag reload loop near-zero cost).
        __syncthreads();
        if (tid == 0)
            __hip_atomic_store(myflag, t + 1, __ATOMIC_RELAXED,
                               __HIP_MEMORY_SCOPE_AGENT);

        // prefetch x_proj for t+1; drains while polling at next step
        if (t < 511 && quad == 0) {
#pragma unroll
            for (int r = 0; r < 4; r++)
                xv[r] = (float)xp[((long)(t + 1) * 64 + b0 + r) * 1024 + dim];
        }
    }
}

extern "C" void kernel_launch(void* const* d_in, const int* in_sizes, int n_in,
                              void* d_out, int out_size, void* d_ws, size_t ws_size,
                              hipStream_t stream) {
    const int*   src = (const int*)d_in[0];
    const float* emb = (const float*)d_in[1];
    const float* Wxh = (const float*)d_in[2];
    const float* bxh = (const float*)d_in[3];
    const float* Whh = (const float*)d_in[4];
    float* out = (float*)d_out;

    char* ws = (char*)d_ws;
    unsigned long long* hb = (unsigned long long*)ws;
    int* flags = (int*)(ws + HBUF_BYTES);
    _Float16* xp = (_Float16*)(ws + XP_OFF);

    // zero h exchange (tag 0 == "h_0 ready, value 0" both parities) + flags
    hipMemsetAsync(ws, 0, HBUF_BYTES + CTL_BYTES, stream);

    hipLaunchKernelGGL(xproj_kernel, dim3(2048), dim3(256), 0, stream,
                       src, emb, Wxh, bxh, xp);

    hipLaunchKernelGGL(rnn_kernel, dim3(256), dim3(256), 0, stream,
                       Whh, xp, hb, flags, out);
}

// Round 8
// 1319.577 us; speedup vs baseline: 1.2560x; 1.2560x over previous
//
#include <hip/hip_runtime.h>
#include <hip/hip_fp16.h>

typedef _Float16 half8 __attribute__((ext_vector_type(8)));
typedef float floatx4 __attribute__((ext_vector_type(4)));

// workspace layout (R4 format: [parity][group][dim] ulong = 4 f16 batches)
#define HBUF_BYTES (2ull * 16 * 1024 * 8)   // 256 KB
#define CTL_BYTES  (32ull * 1024)           // flag words, 64 B each
#define XP_OFF     (HBUF_BYTES + CTL_BYTES)
#define XP_BYTES   (512ull * 64 * 1024 * 2) // x_proj f16 [t][b][dim] = 64 MB
#define FLAG_STRIDE 16                      // ints -> 64 B per member flag

union pack4 { unsigned long long u; _Float16 h[4]; };

__device__ inline half8 cvt8(const float4 a, const float4 b) {
    half8 r;
    r[0] = (_Float16)a.x; r[1] = (_Float16)a.y; r[2] = (_Float16)a.z; r[3] = (_Float16)a.w;
    r[4] = (_Float16)b.x; r[5] = (_Float16)b.y; r[6] = (_Float16)b.z; r[7] = (_Float16)b.w;
    return r;
}

// ---------------------------------------------------------------------------
// Phase A: x_proj[t][b][n] = sum_k emb[src[b][t]][k] * W_xh[n][k] + b_xh[n]
// (unchanged — ~300 us; becomes the target once phase B is < ~0.5 ms)
// ---------------------------------------------------------------------------
__global__ __launch_bounds__(256) void xproj_kernel(
    const int* __restrict__ src, const float* __restrict__ emb,
    const float* __restrict__ Wxh, const float* __restrict__ bxh,
    _Float16* __restrict__ xp)
{
    __shared__ _Float16 As[128][40];
    __shared__ _Float16 Bs[128][40];

    const int tid  = threadIdx.x;
    const int lane = tid & 63;
    const int w    = tid >> 6;
    const int m15  = lane & 15;
    const int quad = lane >> 4;
    const int bid  = blockIdx.x;
    const int bn   = bid & 7;
    const int bm   = bid >> 3;
    const int m0   = bm * 128, n0 = bn * 128;
    const int wm   = w & 1, wn = w >> 1;

    const int  srow = tid >> 1;
    const int  scol = (tid & 1) * 16;
    const long arow = (long)src[m0 + srow] * 1024;
    const float* abase = emb + arow + scol;
    const float* bbase = Wxh + (long)(n0 + srow) * 1024 + scol;

    floatx4 zero4 = {0.f, 0.f, 0.f, 0.f};
    floatx4 acc[4][4];
#pragma unroll
    for (int mt = 0; mt < 4; mt++)
#pragma unroll
        for (int nt = 0; nt < 4; nt++) acc[mt][nt] = zero4;

    for (int k0 = 0; k0 < 1024; k0 += 32) {
        __syncthreads();
        float4 a0 = *(const float4*)(abase + k0);
        float4 a1 = *(const float4*)(abase + k0 + 4);
        float4 a2 = *(const float4*)(abase + k0 + 8);
        float4 a3 = *(const float4*)(abase + k0 + 12);
        float4 b0 = *(const float4*)(bbase + k0);
        float4 b1 = *(const float4*)(bbase + k0 + 4);
        float4 b2 = *(const float4*)(bbase + k0 + 8);
        float4 b3 = *(const float4*)(bbase + k0 + 12);
        *(half8*)&As[srow][scol]     = cvt8(a0, a1);
        *(half8*)&As[srow][scol + 8] = cvt8(a2, a3);
        *(half8*)&Bs[srow][scol]     = cvt8(b0, b1);
        *(half8*)&Bs[srow][scol + 8] = cvt8(b2, b3);
        __syncthreads();

        half8 af[4], bf[4];
#pragma unroll
        for (int mt = 0; mt < 4; mt++)
            af[mt] = *(const half8*)&As[wm * 64 + mt * 16 + m15][quad * 8];
#pragma unroll
        for (int nt = 0; nt < 4; nt++)
            bf[nt] = *(const half8*)&Bs[wn * 64 + nt * 16 + m15][quad * 8];
#pragma unroll
        for (int mt = 0; mt < 4; mt++)
#pragma unroll
            for (int nt = 0; nt < 4; nt++)
                acc[mt][nt] = __builtin_amdgcn_mfma_f32_16x16x32_f16(
                    af[mt], bf[nt], acc[mt][nt], 0, 0, 0);
    }

#pragma unroll
    for (int nt = 0; nt < 4; nt++) {
        const int n = n0 + wn * 64 + nt * 16 + m15;
        const float bias = bxh[n];
#pragma unroll
        for (int mt = 0; mt < 4; mt++) {
            const int mrow = m0 + wm * 64 + mt * 16 + quad * 4;
#pragma unroll
            for (int r = 0; r < 4; r++) {
                const int m = mrow + r;
                const int b = m >> 9;
                const int t = m & 511;
                xp[((long)t * 64 + b) * 1024 + n] = (_Float16)(acc[mt][nt][r] + bias);
            }
        }
    }
}

// ---------------------------------------------------------------------------
// Phase B: persistent recurrence, plain launch (256 WGs, 1 WG/CU guaranteed).
// R8 = R7 retry with fixed asm: loads + s_waitcnt fused into ONE asm block,
// "=&v" early-clobber outputs (standalone tied-operand waitcnt asm doesn't
// compile on gfx950 LLVM).
// Consumer: 2x16B SYSTEM-SCOPE plain loads (sc0 sc1 = bypass L1+L2, read
// MALL point-of-coherence directly — fresh despite stale parity lines).
// Working model (R4/R5/R6 evidence): exchange is MALL-op-THROUGHPUT bound
// (~65 ops/cyc chip-wide); dur tracks op count => halve the dominant term.
// Ordering: producer stores -> __syncthreads (vmcnt(0) drain) -> flag store;
// consumer 16-lane flag poll -> loads. Parity double-buffer: flag=t from X
// proves X finished reading t-1 => overwrite of parity (t+1)&1 safe.
// ---------------------------------------------------------------------------
__global__ __launch_bounds__(256, 1) void rnn_kernel(
    const float* __restrict__ Whh, const _Float16* __restrict__ xp,
    unsigned long long* __restrict__ hb, int* __restrict__ flags,
    float* __restrict__ out)
{
    __shared__ _Float16 hstage[16][1032];       // rows 4..15 stay zero (M-pad)
    __shared__ floatx4  cred[4][4][64];         // [k-slice wave][ntile][lane]

    const int tid    = threadIdx.x;
    const int lane   = tid & 63;
    const int w      = tid >> 6;
    const int m15    = lane & 15;
    const int quad   = lane >> 4;
    const int wg     = blockIdx.x;
    const int g      = wg & 15;
    const int member = wg >> 4;
    const int b0     = g * 4;

    for (int i = tid; i < 16 * 1032; i += 256) ((_Float16*)hstage)[i] = (_Float16)0.f;

    // W_hh slice -> 128 VGPRs (f16), reused for all 512 steps
    half8 Wf[4][8];
#pragma unroll
    for (int nt = 0; nt < 4; nt++) {
        const float* wrow = Whh + (long)(member * 64 + nt * 16 + m15) * 1024
                                + w * 256 + quad * 8;
#pragma unroll
        for (int kk = 0; kk < 8; kk++) {
            float4 lo = *(const float4*)(wrow + kk * 32);
            float4 hi = *(const float4*)(wrow + kk * 32 + 4);
            Wf[nt][kk] = cvt8(lo, hi);
        }
    }
    __syncthreads();

    const int dim = member * 64 + w * 16 + m15;
    float xv[4] = {0.f, 0.f, 0.f, 0.f};
    if (quad == 0) {
#pragma unroll
        for (int r = 0; r < 4; r++)
            xv[r] = (float)xp[((long)0 * 64 + b0 + r) * 1024 + dim];
    }

    int* myflag = flags + (g * 16 + member) * FLAG_STRIDE;
    const int* gflags = flags + g * 16 * FLAG_STRIDE;
    floatx4 zero4 = {0.f, 0.f, 0.f, 0.f};

    for (int t = 0; t < 512; t++) {
        if (t > 0) {
            // parallel poll: lane m watches member m's flag (quiesced lines)
            if (tid < 16) {
                const int* fw = gflags + tid * FLAG_STRIDE;
                while (__hip_atomic_load(fw, __ATOMIC_RELAXED,
                                         __HIP_MEMORY_SCOPE_AGENT) < t) { }
            }
            __syncthreads();
        }

        // gather h_t: thread tid owns dims 4*tid..4*tid+3 (32 B contiguous).
        // Two 16B system-scope loads (sc0 sc1): bypass L1+L2, read MALL.
        {
            const unsigned long long* hcu =
                hb + (size_t)(t & 1) * 16384 + (size_t)g * 1024 + (size_t)tid * 4;
            uint4 v0, v1;
            asm volatile(
                "global_load_dwordx4 %0, %2, off sc0 sc1\n\t"
                "global_load_dwordx4 %1, %2, off offset:16 sc0 sc1\n\t"
                "s_waitcnt vmcnt(0)"
                : "=&v"(v0), "=&v"(v1)
                : "v"(hcu)
                : "memory");

            unsigned long long u[4];
            u[0] = ((unsigned long long)v0.y << 32) | v0.x;
            u[1] = ((unsigned long long)v0.w << 32) | v0.z;
            u[2] = ((unsigned long long)v1.y << 32) | v1.x;
            u[3] = ((unsigned long long)v1.w << 32) | v1.z;
            // word e holds dim 4*tid+e, batches in bits [16b..16b+15]
#pragma unroll
            for (int b = 0; b < 4; b++) {
                unsigned long long q = 0;
#pragma unroll
                for (int e = 0; e < 4; e++)
                    q |= ((u[e] >> (16 * b)) & 0xffffull) << (16 * e);
                *(unsigned long long*)&hstage[b][tid * 4] = q;
            }
        }
        __syncthreads();

        // partial GEMM over this wave's K-slice, 4 n-tiles
        floatx4 pacc[4];
#pragma unroll
        for (int nt = 0; nt < 4; nt++) pacc[nt] = zero4;
#pragma unroll
        for (int kk = 0; kk < 8; kk++) {
            half8 a = *(const half8*)&hstage[m15][w * 256 + kk * 32 + quad * 8];
#pragma unroll
            for (int nt = 0; nt < 4; nt++)
                pacc[nt] = __builtin_amdgcn_mfma_f32_16x16x32_f16(
                    a, Wf[nt][kk], pacc[nt], 0, 0, 0);
        }

        // cross-wave K reduction via LDS; wave w finalizes n-tile w
#pragma unroll
        for (int nt = 0; nt < 4; nt++) cred[w][nt][lane] = pacc[nt];
        __syncthreads();
        floatx4 dsum = cred[0][w][lane];
#pragma unroll
        for (int ww = 1; ww < 4; ww++) dsum += cred[ww][w][lane];

        // epilogue: quad 0 holds batches 0..3; pack + one 8B atomic store
        if (quad == 0) {
            pack4 p;
#pragma unroll
            for (int r = 0; r < 4; r++) {
                float pre  = dsum[r] + xv[r];
                float e    = __expf(2.0f * pre);
                float hval = 1.0f - 2.0f / (e + 1.0f);   // tanh
                p.h[r] = (_Float16)hval;
                if (t == 511) out[(b0 + r) * 1024 + dim] = hval;
            }
            unsigned long long* hnu =
                hb + (size_t)((t + 1) & 1) * 16384 + (size_t)g * 1024;
            __hip_atomic_store(hnu + dim, p.u, __ATOMIC_RELAXED,
                               __HIP_MEMORY_SCOPE_AGENT);
        }

        // publish: barrier drains every wave's vmcnt(0) -> h stores acked,
        // then one relaxed flag store.
        __syncthreads();
        if (tid == 0)
            __hip_atomic_store(myflag, t + 1, __ATOMIC_RELAXED,
                               __HIP_MEMORY_SCOPE_AGENT);

        // prefetch x_proj for t+1; drains while polling at next step
        if (t < 511 && quad == 0) {
#pragma unroll
            for (int r = 0; r < 4; r++)
                xv[r] = (float)xp[((long)(t + 1) * 64 + b0 + r) * 1024 + dim];
        }
    }
}

extern "C" void kernel_launch(void* const* d_in, const int* in_sizes, int n_in,
                              void* d_out, int out_size, void* d_ws, size_t ws_size,
                              hipStream_t stream) {
    const int*   src = (const int*)d_in[0];
    const float* emb = (const float*)d_in[1];
    const float* Wxh = (const float*)d_in[2];
    const float* bxh = (const float*)d_in[3];
    const float* Whh = (const float*)d_in[4];
    float* out = (float*)d_out;

    char* ws = (char*)d_ws;
    unsigned long long* hb = (unsigned long long*)ws;
    int* flags = (int*)(ws + HBUF_BYTES);
    _Float16* xp = (_Float16*)(ws + XP_OFF);

    // zero h[0] (f16 zeros are bit-zero) and flag words
    (void)hipMemsetAsync(ws, 0, HBUF_BYTES + CTL_BYTES, stream);

    hipLaunchKernelGGL(xproj_kernel, dim3(2048), dim3(256), 0, stream,
                       src, emb, Wxh, bxh, xp);

    hipLaunchKernelGGL(rnn_kernel, dim3(256), dim3(256), 0, stream,
                       Whh, xp, hb, flags, out);
}